// Round 12
// baseline (327.381 us; speedup 1.0000x reference)
//
#include <hip/hip_runtime.h>

// WaveRNN single-step forward, MI355X gfx950.
// bf16 MFMA GEMMs. GRU fused kernel: 8 waves gate-specialized, BM=128/BN=64,
// TRIPLE-buffered staging (120KB dynamic LDS), prefetch depth 2, counted
// s_waitcnt vmcnt(5) + raw s_barrier per K-step (never drain in-loop).
// Workspace: 107,085,824 B.

#define BK 32

typedef __attribute__((ext_vector_type(8))) short short8;
typedef __attribute__((ext_vector_type(4))) float f32x4;
typedef __attribute__((ext_vector_type(8))) unsigned short ush8;

__device__ __forceinline__ unsigned short f2bf(float f) {
    unsigned int u = __float_as_uint(f);
    u += 0x7fffu + ((u >> 16) & 1u);      // RNE
    return (unsigned short)(u >> 16);
}
__device__ __forceinline__ float bf2f(unsigned short h) {
    return __uint_as_float(((unsigned int)h) << 16);
}
__device__ __forceinline__ float sigm(float x)  { return 1.f / (1.f + __expf(-x)); }
__device__ __forceinline__ float tanh_f(float x){ return 1.f - 2.f / (__expf(2.f * x) + 1.f); }

__device__ __forceinline__ void gl16(const void* g, void* l) {
    __builtin_amdgcn_global_load_lds(
        (const __attribute__((address_space(1))) unsigned int*)g,
        (__attribute__((address_space(3))) unsigned int*)l, 16, 0, 0);
}

// ---------------- fused GRU cell kernel ----------------
// 512 thr / 8 waves. Block: 128 rows x 64 cols x 3 gates (gi+gh).
// Buffer (40KB): A1[128][32] | A2[128][32] | B[6][64][32]; 3 buffers (120KB).
// Staging: 2560 16B-units/buffer, 5 gl16/thread, unit u = k*512 + w*64 + lane.
struct GruArgs {
    const float* hprev;       // [8192][512] f32
    const float* xprev;       // [8192][512] f32
    float* hn_out;            // d_out slice
    float* x_f32_out;         // nullable
    unsigned short* x_bf_out; // bf16 X out
    int out_stride;           // 576
};

__global__ __launch_bounds__(512)
void gru_k(const unsigned short* __restrict__ A1, const unsigned short* __restrict__ A2,
           const unsigned short* __restrict__ Wih, const unsigned short* __restrict__ Whh,
           const float* __restrict__ bih, const float* __restrict__ bhh,
           int kpad, GruArgs g)
{
    extern __shared__ __align__(16) unsigned short lds[];
    constexpr int BUFU = 20480;               // ushorts per buffer (40KB)
    const int t    = threadIdx.x;
    const int w    = t >> 6;
    const int lane = t & 63;
    const int isgi = (w < 4);
    const int ww   = w & 3;
    const int mh   = ww >> 1;                 // 0/1: 64-row half
    const int nh   = ww & 1;                  // 0/1: 32-col half
    const int m0   = blockIdx.x * 128;
    const int n0   = blockIdx.y * 64;
    const int fr   = lane & 15;
    const int kg   = (lane >> 4) * 8;
    const int NT   = kpad >> 5;

    f32x4 acc[3][4][2] = {};

    auto stage = [&](int buf, int k0) {
        unsigned short* dst = lds + buf * BUFU;
        #pragma unroll
        for (int k = 0; k < 5; ++k) {
            const int u = k * 512 + w * 64 + lane;
            const unsigned short* src;
            if (u < 512) {
                src = A1 + (size_t)(m0 + (u >> 2)) * kpad + k0 + (u & 3) * 8;
            } else if (u < 1024) {
                src = A2 + (size_t)(m0 + ((u - 512) >> 2)) * kpad + k0 + (u & 3) * 8;
            } else {
                const int v = u - 1024;
                const int p = v >> 8;                       // panel 0..5
                const int r = (v & 255) >> 2;               // row 0..63
                const unsigned short* Wp = (p < 3) ? Wih : Whh;
                const int s = (p < 3) ? p : p - 3;
                src = Wp + (size_t)(s * 512 + n0 + r) * kpad + k0 + (u & 3) * 8;
            }
            gl16(src, dst + (size_t)(k * 512 + w * 64) * 8);   // HW adds lane*16B
        }
    };

    // prologue: prefetch tiles 0 and 1; wait only for tile 0 (5 newest stay in flight)
    stage(0, 0);
    stage(1, BK);
    __builtin_amdgcn_sched_barrier(0);
    asm volatile("s_waitcnt vmcnt(5)" ::: "memory");
    __builtin_amdgcn_s_barrier();
    __builtin_amdgcn_sched_barrier(0);

    int cur = 0;
    for (int tt = 0; tt < NT; ++tt) {
        const int nxt2 = (cur + 2 >= 3) ? cur - 1 : cur + 2;
        if (tt + 2 < NT) stage(nxt2, (tt + 2) * BK);
        const unsigned short* B0 = lds + cur * BUFU;
        const unsigned short* Ab = B0 + (isgi ? 0 : 4096);
        short8 a[4];
        #pragma unroll
        for (int mi = 0; mi < 4; ++mi)
            a[mi] = *(const short8*)(Ab + (mh * 64 + mi * 16 + fr) * 32 + kg);
        #pragma unroll
        for (int s = 0; s < 3; ++s) {
            const unsigned short* Bp = B0 + 8192 + (isgi ? s : s + 3) * 2048;
            #pragma unroll
            for (int ni = 0; ni < 2; ++ni) {
                short8 b = *(const short8*)(Bp + (nh * 32 + ni * 16 + fr) * 32 + kg);
                #pragma unroll
                for (int mi = 0; mi < 4; ++mi)
                    acc[s][mi][ni] = __builtin_amdgcn_mfma_f32_16x16x32_bf16(a[mi], b, acc[s][mi][ni], 0, 0, 0);
            }
        }
        // pin compute above; wait for batch t+1 (leave batch t+2's 5 loads in flight)
        __builtin_amdgcn_sched_barrier(0);
        if (tt + 2 < NT) asm volatile("s_waitcnt vmcnt(5)" ::: "memory");
        else             asm volatile("s_waitcnt vmcnt(0)" ::: "memory");
        __builtin_amdgcn_s_barrier();
        __builtin_amdgcn_sched_barrier(0);
        cur = (cur + 1 >= 3) ? 0 : cur + 1;
    }

    // ---- epilogue: gh waves hand partials to gi waves via LDS ----
    float* xf = (float*)lds;
    // f32 slot: set_region*8192 + ww*2048 + (mi*2+ni)*256 + lane*4
    if (!isgi) {
        #pragma unroll
        for (int s = 0; s < 2; ++s)
        #pragma unroll
        for (int mi = 0; mi < 4; ++mi)
        #pragma unroll
        for (int ni = 0; ni < 2; ++ni)
            *(f32x4*)(xf + s * 8192 + ww * 2048 + (mi * 2 + ni) * 256 + lane * 4) = acc[s][mi][ni];
    }
    __syncthreads();
    if (isgi) {
        #pragma unroll
        for (int mi = 0; mi < 4; ++mi)
        #pragma unroll
        for (int ni = 0; ni < 2; ++ni) {
            const int nn = n0 + nh * 32 + ni * 16 + fr;
            const float bir = bih[nn] + bhh[nn];
            const float biz = bih[512 + nn] + bhh[512 + nn];
            f32x4 ghr = *(const f32x4*)(xf + ww * 2048 + (mi * 2 + ni) * 256 + lane * 4);
            f32x4 ghz = *(const f32x4*)(xf + 8192 + ww * 2048 + (mi * 2 + ni) * 256 + lane * 4);
            #pragma unroll
            for (int v = 0; v < 4; ++v) {
                acc[0][mi][ni][v] = sigm(acc[0][mi][ni][v] + ghr[v] + bir);
                acc[1][mi][ni][v] = sigm(acc[1][mi][ni][v] + ghz[v] + biz);
            }
        }
    }
    __syncthreads();
    if (!isgi) {
        #pragma unroll
        for (int mi = 0; mi < 4; ++mi)
        #pragma unroll
        for (int ni = 0; ni < 2; ++ni)
            *(f32x4*)(xf + ww * 2048 + (mi * 2 + ni) * 256 + lane * 4) = acc[2][mi][ni];
    }
    __syncthreads();
    if (isgi) {
        #pragma unroll
        for (int mi = 0; mi < 4; ++mi)
        #pragma unroll
        for (int ni = 0; ni < 2; ++ni) {
            const int nn = n0 + nh * 32 + ni * 16 + fr;
            const float bin_ = bih[1024 + nn];
            const float bhn  = bhh[1024 + nn];
            f32x4 ghn = *(const f32x4*)(xf + ww * 2048 + (mi * 2 + ni) * 256 + lane * 4);
            #pragma unroll
            for (int v = 0; v < 4; ++v) {
                const int m = m0 + mh * 64 + mi * 16 + (lane >> 4) * 4 + v;
                const size_t r0 = (size_t)m * 512;
                float r  = acc[0][mi][ni][v];
                float z  = acc[1][mi][ni][v];
                float nv = tanh_f(acc[2][mi][ni][v] + bin_ + r * (ghn[v] + bhn));
                float h  = g.hprev[r0 + nn];
                float hv = (1.f - z) * nv + z * h;
                g.hn_out[r0 + nn] = hv;
                float xv = g.xprev[r0 + nn] + hv;
                if (g.x_f32_out) g.x_f32_out[r0 + nn] = xv;
                g.x_bf_out[(size_t)m * g.out_stride + nn] = f2bf(xv);
            }
        }
    }
}

// ---------------- generic single-set GEMM ----------------
// EPI: 0 = f32 + bf16 out (I layer); 3 = relu bf16; 4 = f32 out (logits)
struct EpiArgs { float* f32_out; unsigned short* bf_h; int out_stride; };

template<int EPI>
__global__ __launch_bounds__(256)
void gemm_k(const unsigned short* __restrict__ A, const unsigned short* __restrict__ W,
            const float* __restrict__ bias, int kpad, EpiArgs ea)
{
    constexpr int BUFU = 8 * 512;
    __shared__ __align__(16) unsigned short lds[2 * BUFU];
    const int t    = threadIdx.x;
    const int m0   = blockIdx.x * 64;
    const int n0   = blockIdx.y * 64;
    const int lane = t & 63;
    const int w    = t >> 6;
    const int rl   = lane >> 2;
    const int cl   = (lane & 3) * 8;
    const int fr   = lane & 15;
    const int kg   = (lane >> 4) * 8;

    f32x4 acc[4] = {};
    const int NT = kpad >> 5;

    auto stage = [&](int buf, int k0) {
        unsigned short* dst = lds + buf * BUFU;
        gl16(A + (size_t)(m0 + w * 16 + rl) * kpad + (k0 + cl), dst + w * 512);
        gl16(W + (size_t)(n0 + w * 16 + rl) * kpad + (k0 + cl), dst + (4 + w) * 512);
    };

    stage(0, 0);
    __syncthreads();
    int cur = 0;
    for (int tt = 0; tt < NT; ++tt) {
        if (tt + 1 < NT) stage(cur ^ 1, (tt + 1) * BK);
        const unsigned short* Bb = lds + cur * BUFU;
        short8 b = *(const short8*)(Bb + 2048 + (w * 16 + fr) * 32 + kg);
        #pragma unroll
        for (int mi = 0; mi < 4; ++mi) {
            short8 a = *(const short8*)(Bb + (mi * 16 + fr) * 32 + kg);
            acc[mi] = __builtin_amdgcn_mfma_f32_16x16x32_bf16(a, b, acc[mi], 0, 0, 0);
        }
        __syncthreads();
        cur ^= 1;
    }

    const int nn = n0 + w * 16 + fr;
    const float bv = bias[nn];
    #pragma unroll
    for (int mi = 0; mi < 4; ++mi)
    #pragma unroll
    for (int v = 0; v < 4; ++v) {
        const int m = m0 + mi * 16 + (lane >> 4) * 4 + v;
        float val = acc[mi][v] + bv;
        if constexpr (EPI == 0) {
            const size_t o = (size_t)m * 512 + nn;
            ea.f32_out[o] = val;
            ea.bf_h[o] = f2bf(val);
        } else if constexpr (EPI == 3) {
            val = fmaxf(val, 0.f);
            ea.bf_h[(size_t)m * ea.out_stride + nn] = f2bf(val);
        } else {
            ea.f32_out[(size_t)m * 512 + nn] = val;
        }
    }
}

// ---------------- preprocessing ----------------
struct SplitSeg { const float* src; unsigned short* dh; int K; int Kpad; int total; };
struct SplitArgs { SplitSeg seg[10]; };

__global__ void k_split(SplitArgs a) {
    const SplitSeg s = a.seg[blockIdx.y];
    const int stride = gridDim.x * blockDim.x;
    const int tid0 = blockIdx.x * blockDim.x + threadIdx.x;
    if ((s.K & 7) == 0) {                      // vectorized (K, Kpad both %8==0)
        const int n8 = s.total >> 3;
        const int kp8 = s.Kpad >> 3;
        const int k8  = s.K >> 3;
        ush8* dst8 = (ush8*)s.dh;
        for (int i = tid0; i < n8; i += stride) {
            ush8 o;
            int row = i / kp8;
            int c8  = i - row * kp8;
            if (c8 < k8) {
                const float4* src4 = (const float4*)(s.src + (size_t)row * s.K + c8 * 8);
                float4 f0 = src4[0];
                float4 f1 = src4[1];
                o[0] = f2bf(f0.x); o[1] = f2bf(f0.y); o[2] = f2bf(f0.z); o[3] = f2bf(f0.w);
                o[4] = f2bf(f1.x); o[5] = f2bf(f1.y); o[6] = f2bf(f1.z); o[7] = f2bf(f1.w);
            } else {
                o = ush8{0, 0, 0, 0, 0, 0, 0, 0};
            }
            dst8[i] = o;
        }
    } else {                                   // scalar fallback (I_w: K=113)
        for (int i = tid0; i < s.total; i += stride) {
            int row = i / s.Kpad;
            int col = i - row * s.Kpad;
            float v = (col < s.K) ? s.src[(size_t)row * s.K + col] : 0.f;
            s.dh[i] = f2bf(v);
        }
    }
}

__global__ void k_build_c0(const float* __restrict__ x, const float* __restrict__ m,
                           const float* __restrict__ a1, unsigned short* __restrict__ dh) {
    int i = blockIdx.x * blockDim.x + threadIdx.x;   // 8192*128
    int row = i >> 7, col = i & 127;
    float v = 0.f;
    if (col == 0)       v = x[row];
    else if (col < 81)  v = m[row * 80 + (col - 1)];
    else if (col < 113) v = a1[row * 32 + (col - 81)];
    dh[i] = f2bf(v);
}

__global__ void k_fill_tail(unsigned short* __restrict__ dh, const float* __restrict__ src) {
    int i = blockIdx.x * blockDim.x + threadIdx.x;   // 8192*64 -> cols 512..575 of 576-wide
    int row = i >> 6, col = i & 63;
    float v = (col < 32) ? src[row * 32 + col] : 0.f;
    dh[(size_t)row * 576 + 512 + col] = f2bf(v);
}

extern "C" void kernel_launch(void* const* d_in, const int* in_sizes, int n_in,
                              void* d_out, int out_size, void* d_ws, size_t ws_size,
                              hipStream_t stream)
{
    // ---- workspace layout (bytes), total 107,085,824, no aliasing ----
    const size_t OFF_WI   = 0;           // 512x128  bf16
    const size_t OFF_W1IH = 131072;      // 1536x512 bf16
    const size_t OFF_W1HH = 1703936;     // 1536x512 bf16
    const size_t OFF_W2IH = 3276800;     // 1536x576 bf16
    const size_t OFF_W2HH = 5046272;     // 1536x576 bf16 (K 512->576 zero-pad)
    const size_t OFF_WFC1 = 6815744;     // 512x576 bf16
    const size_t OFF_WFC2 = 7405568;     // 512x576 bf16
    const size_t OFF_WFC3 = 7995392;     // 512x512 bf16
    const size_t OFF_H1   = 8519680;     // 8192x512 bf16
    const size_t OFF_H2   = 16908288;    // 8192x576 bf16 (zero-pad)
    const size_t OFF_C0   = 26345472;    // 8192x128 bf16
    const size_t OFF_X0H  = 28442624;    // 8192x512 bf16
    const size_t OFF_X0F  = 36831232;    // 8192x512 f32
    const size_t OFF_X1F  = 53608448;    // 8192x512 f32
    const size_t OFF_X1C  = 70385664;    // 8192x576 bf16
    const size_t OFF_X2C  = 79822848;    // 8192x576 bf16
    const size_t OFF_X3C  = 89260032;    // 8192x576 bf16
    const size_t OFF_X4   = 98697216;    // 8192x512 bf16
    const size_t WS_NEEDED = 107085824;
    if (ws_size < WS_NEEDED) return;     // clean-fail guard (constant per call)

    const float* m_t   = (const float*)d_in[0];
    const float* a1    = (const float*)d_in[1];
    const float* a2    = (const float*)d_in[2];
    const float* a3    = (const float*)d_in[3];
    const float* a4    = (const float*)d_in[4];
    const float* h1    = (const float*)d_in[5];
    const float* h2    = (const float*)d_in[6];
    const float* xin   = (const float*)d_in[7];
    const float* I_w   = (const float*)d_in[8];
    const float* I_b   = (const float*)d_in[9];
    const float* r1wih = (const float*)d_in[10];
    const float* r1whh = (const float*)d_in[11];
    const float* r1bih = (const float*)d_in[12];
    const float* r1bhh = (const float*)d_in[13];
    const float* r2wih = (const float*)d_in[14];
    const float* r2whh = (const float*)d_in[15];
    const float* r2bih = (const float*)d_in[16];
    const float* r2bhh = (const float*)d_in[17];
    const float* fc1w  = (const float*)d_in[18];
    const float* fc1b  = (const float*)d_in[19];
    const float* fc2w  = (const float*)d_in[20];
    const float* fc2b  = (const float*)d_in[21];
    const float* fc3w  = (const float*)d_in[22];
    const float* fc3b  = (const float*)d_in[23];
    float* out = (float*)d_out;

    char* ws = (char*)d_ws;
    auto U  = [&](size_t off) { return (unsigned short*)(ws + off); };
    auto Fp = [&](size_t off) { return (float*)(ws + off); };
    (void)in_sizes; (void)n_in; (void)out_size;

    // 1) cast/pad weights + h1/h2 to bf16
    SplitArgs sa;
    sa.seg[0] = { I_w,   U(OFF_WI),   113, 128, 512 * 128 };
    sa.seg[1] = { r1wih, U(OFF_W1IH), 512, 512, 1536 * 512 };
    sa.seg[2] = { r1whh, U(OFF_W1HH), 512, 512, 1536 * 512 };
    sa.seg[3] = { r2wih, U(OFF_W2IH), 544, 576, 1536 * 576 };
    sa.seg[4] = { r2whh, U(OFF_W2HH), 512, 576, 1536 * 576 };
    sa.seg[5] = { fc1w,  U(OFF_WFC1), 544, 576, 512 * 576 };
    sa.seg[6] = { fc2w,  U(OFF_WFC2), 544, 576, 512 * 576 };
    sa.seg[7] = { fc3w,  U(OFF_WFC3), 512, 512, 512 * 512 };
    sa.seg[8] = { h1,    U(OFF_H1),   512, 512, 8192 * 512 };
    sa.seg[9] = { h2,    U(OFF_H2),   512, 576, 8192 * 576 };
    hipLaunchKernelGGL(k_split, dim3(512, 10), dim3(256), 0, stream, sa);

    // 2) C0 = [x | m_t | a1 | pad];  aux tails of X1C/X2C/X3C
    hipLaunchKernelGGL(k_build_c0, dim3(4096), dim3(256), 0, stream, xin, m_t, a1, U(OFF_C0));
    hipLaunchKernelGGL(k_fill_tail, dim3(2048), dim3(256), 0, stream, U(OFF_X1C), a2);
    hipLaunchKernelGGL(k_fill_tail, dim3(2048), dim3(256), 0, stream, U(OFF_X2C), a3);
    hipLaunchKernelGGL(k_fill_tail, dim3(2048), dim3(256), 0, stream, U(OFF_X3C), a4);

    // 3) G1: X0 = C0 @ I_w.T + I_b   (f32 + bf16)
    EpiArgs ea{};
    ea.f32_out = Fp(OFF_X0F); ea.bf_h = U(OFF_X0H); ea.out_stride = 512;
    hipLaunchKernelGGL((gemm_k<0>), dim3(128, 8), dim3(256), 0, stream,
                       U(OFF_C0), U(OFF_WI), I_b, 128, ea);

    // 4) GRU1 fused -> h1n (out), X1 (f32 + bf16 into X1C)
    GruArgs g{};
    g.hprev = h1; g.xprev = Fp(OFF_X0F);
    g.hn_out = out + 4194304; g.x_f32_out = Fp(OFF_X1F);
    g.x_bf_out = U(OFF_X1C); g.out_stride = 576;
    hipLaunchKernelGGL(gru_k, dim3(64, 8), dim3(512), 122880, stream,
                       U(OFF_X0H), U(OFF_H1), U(OFF_W1IH), U(OFF_W1HH), r1bih, r1bhh, 512, g);

    // 5) GRU2 fused -> h2n (out), X2 (bf16 into X2C)
    g = GruArgs{};
    g.hprev = h2; g.xprev = Fp(OFF_X1F);
    g.hn_out = out + 8388608; g.x_f32_out = nullptr;
    g.x_bf_out = U(OFF_X2C); g.out_stride = 576;
    hipLaunchKernelGGL(gru_k, dim3(64, 8), dim3(512), 122880, stream,
                       U(OFF_X1C), U(OFF_H2), U(OFF_W2IH), U(OFF_W2HH), r2bih, r2bhh, 576, g);

    // 6) fc1 relu -> X3C
    ea = EpiArgs{}; ea.bf_h = U(OFF_X3C); ea.out_stride = 576;
    hipLaunchKernelGGL((gemm_k<3>), dim3(128, 8), dim3(256), 0, stream,
                       U(OFF_X2C), U(OFF_WFC1), fc1b, 576, ea);
    // 7) fc2 relu -> X4
    ea = EpiArgs{}; ea.bf_h = U(OFF_X4); ea.out_stride = 512;
    hipLaunchKernelGGL((gemm_k<3>), dim3(128, 8), dim3(256), 0, stream,
                       U(OFF_X3C), U(OFF_WFC2), fc2b, 576, ea);
    // 8) fc3 logits -> d_out[0:4194304]
    ea = EpiArgs{}; ea.f32_out = out;
    hipLaunchKernelGGL((gemm_k<4>), dim3(128, 8), dim3(256), 0, stream,
                       U(OFF_X4), U(OFF_WFC3), fc3b, 512, ea);
}